// Round 3
// baseline (1071.595 us; speedup 1.0000x reference)
//
#include <hip/hip_runtime.h>
#include <math.h>

#define BATCH 16
#define SEQ   720
#define ENC   321
#define NORD  64
#define PRED  720
#define NPAIR (BATCH*ENC)   // 5136

// workspace layout (float offsets)
#define WS_MEAN   0
#define WS_RSTD   (WS_MEAN + NPAIR)        // 5136
#define WS_STDEV  (WS_RSTD + NPAIR)        // 10272
#define WS_KT     (WS_STDEV + NPAIR)       // 15408  (720x64, t-major: K[t][m] = (A^(719-t) B)[m])
#define WS_EW     (WS_KT + PRED*NORD)      // 61488  (720x64: EW[t'][m] = sum_n eval[t'][n] W[n][m])
#define WS_EVB    (WS_EW + PRED*NORD)      // 107568 (720: eval[t']·b_mlp)
#define WS_C      (WS_EVB + PRED)          // 108288 (5136x64: c_final per pair)

#define NSTATS 96     // 16 b * 6 e-tiles(64)
#define NEWB   12     // EW blocks (60 t' rows each)

// ---------------- Kernel 1 (fused): stats | EW | Krylov build ----------------
__global__ __launch_bounds__(1024) void k1(const float* __restrict__ x,
        const float* __restrict__ A, const float* __restrict__ Bv,
        const float* __restrict__ evalm, const float* __restrict__ W,
        const float* __restrict__ bm, float* __restrict__ ws)
{
    extern __shared__ float sm[];
    const int tid  = threadIdx.x;
    const int lane = tid & 63;
    const int wv   = tid >> 6;       // wave id 0..15
    const int bid  = blockIdx.x;

    if (bid < NSTATS) {
        // -------- RevIN stats for 64 e's of one batch --------
        const int b = bid / 6, et = bid % 6;
        const int e = et*64 + lane;
        const bool valid = e < ENC;
        float sum = 0.f, ss = 0.f;
        if (valid) {
            const float* xp = x + (size_t)b*SEQ*ENC + e;
            for (int t = wv; t < SEQ; t += 16) {
                float v = xp[(size_t)t*ENC];
                sum += v; ss += v*v;
            }
        }
        float* r1 = sm; float* r2 = sm + 1024;
        r1[wv*64+lane] = sum; r2[wv*64+lane] = ss;
        __syncthreads();
        if (wv == 0 && valid) {
            float s = 0.f, q = 0.f;
            #pragma unroll
            for (int k = 0; k < 16; k++) { s += r1[k*64+lane]; q += r2[k*64+lane]; }
            float mean = s * (1.0f/SEQ);
            float var  = q * (1.0f/SEQ) - mean*mean;
            float sd   = sqrtf(var + 1e-5f);
            int p = b*ENC + e;
            ws[WS_MEAN  + p] = mean;
            ws[WS_STDEV + p] = sd;
            ws[WS_RSTD  + p] = 1.0f / sd;
        }
    } else if (bid < NSTATS + NEWB) {
        // -------- EW = eval @ W  (fold MLP into eval side), evb = eval @ b --------
        const int r = bid - NSTATS;
        for (int idx = tid; idx < 64*64; idx += 1024) {
            int n = idx >> 6, m = idx & 63;
            sm[n*65 + m] = W[idx];
        }
        __syncthreads();
        float bv = bm[lane];
        #pragma unroll
        for (int k = 0; k < 4; k++) {
            int row = wv + k*16;
            if (row < 60) {
                int tp = r*60 + row;
                const float* ev = evalm + (size_t)tp*64;
                float acc = 0.f;
                #pragma unroll
                for (int kk = 0; kk < 16; kk++) {
                    float4 e4 = *(const float4*)&ev[4*kk];
                    acc += e4.x*sm[(4*kk+0)*65+lane] + e4.y*sm[(4*kk+1)*65+lane]
                         + e4.z*sm[(4*kk+2)*65+lane] + e4.w*sm[(4*kk+3)*65+lane];
                }
                ws[WS_EW + (size_t)tp*64 + lane] = acc;
                float pv = ev[lane] * bv;
                #pragma unroll
                for (int o = 32; o > 0; o >>= 1) pv += __shfl_down(pv, o);
                if (lane == 0) ws[WS_EVB + tp] = pv;
            }
        }
    } else {
        // -------- Krylov build: K[j] = A^j B by doubling; store t-major at 719-j --------
        float* Kl  = sm;                    // [256][64] rows j=0..255 (only these re-read)
        float* Ap  = sm + 256*64;           // [64][68]  A^m
        float* ApT = Ap + 64*68;            // [64][68]  (A^m)^T
        float* Kt  = ws + WS_KT;
        for (int idx = tid; idx < 64*64; idx += 1024) {
            int n = idx >> 6, m = idx & 63;
            float v = A[idx];
            Ap[n*68+m] = v; ApT[m*68+n] = v;
        }
        if (tid < 64) {
            float bv = Bv[tid];
            Kl[tid] = bv;
            Kt[(size_t)719*64 + tid] = bv;
        }
        __syncthreads();
        float ar[64];                        // register cache: row `lane` of A^m
        #pragma unroll
        for (int k = 0; k < 16; k++) {
            float4 v = *(const float4*)&Ap[lane*68 + 4*k];
            ar[4*k]=v.x; ar[4*k+1]=v.y; ar[4*k+2]=v.z; ar[4*k+3]=v.w;
        }
        int m = 1;
        while (m < 720) {
            const int hi = (2*m < 720) ? 2*m : 720;
            for (int j2 = m + wv; j2 < hi; j2 += 16) {
                const float* src = &Kl[(j2 - m)*64];
                float acc = 0.f;
                #pragma unroll
                for (int k = 0; k < 16; k++) {
                    float4 s = *(const float4*)&src[4*k];  // wave-uniform broadcast
                    acc += ar[4*k]*s.x + ar[4*k+1]*s.y + ar[4*k+2]*s.z + ar[4*k+3]*s.w;
                }
                if (j2 < 256) Kl[j2*64 + lane] = acc;
                Kt[(size_t)(719 - j2)*64 + lane] = acc;
            }
            const bool sq = (hi < 720);
            float nacc[4];
            if (sq) {
                #pragma unroll
                for (int q = 0; q < 4; q++) {
                    int c = wv*4 + q;
                    const float* src = &ApT[c*68];
                    float acc = 0.f;
                    #pragma unroll
                    for (int k = 0; k < 16; k++) {
                        float4 s = *(const float4*)&src[4*k];
                        acc += ar[4*k]*s.x + ar[4*k+1]*s.y + ar[4*k+2]*s.z + ar[4*k+3]*s.w;
                    }
                    nacc[q] = acc;
                }
            }
            __syncthreads();
            if (sq) {
                #pragma unroll
                for (int q = 0; q < 4; q++) {
                    int c = wv*4 + q;
                    Ap[lane*68 + c]  = nacc[q];
                    ApT[c*68 + lane] = nacc[q];
                }
            }
            __syncthreads();
            if (sq) {
                #pragma unroll
                for (int k = 0; k < 16; k++) {
                    float4 v = *(const float4*)&Ap[lane*68 + 4*k];
                    ar[4*k]=v.x; ar[4*k+1]=v.y; ar[4*k+2]=v.z; ar[4*k+3]=v.w;
                }
            }
            m = hi;
        }
    }
}

// ---------------- Kernel 2: C[p][m] = sum_t f[p][t] * K[t][m]  (NO atomics) ----------------
// grid 16b x 11 e-tiles(32); 512 thr; full t=720 per block; double-buffered LDS.
#define ETILE 32
#define TCH   60
#define NCH   12
__global__ __launch_bounds__(512) void k2(const float* __restrict__ x,
        const float* __restrict__ aw, const float* __restrict__ ab,
        float* __restrict__ ws)
{
    __shared__ float xt[2][TCH*ETILE];   // f tile [tt][ee], scale/shift pre-applied
    __shared__ float Ks[2][TCH*64];      // K tile [tt][m]
    const int tid = threadIdx.x;
    const int b   = blockIdx.x / 11;
    const int et  = blockIdx.x % 11;
    const int e0  = et*ETILE;

    // staging roles
    const int  sx_t  = tid >> 3;            // 0..63 (used if <60)
    const int  sx_e  = (tid & 7) * 4;
    const bool sx_on = tid < 480;           // 480 = 60*32/4

    // fold (mean,rstd,affine) into scale/shift for the 4 staged e's
    float sc[4], sh[4];
    #pragma unroll
    for (int j = 0; j < 4; j++) {
        int e = e0 + sx_e + j;
        if (e < ENC) {
            int p = b*ENC + e;
            float rs = ws[WS_RSTD + p];
            float mn = ws[WS_MEAN + p];
            float a  = aw[e];
            sc[j] = rs * a;
            sh[j] = ab[e] - mn * rs * a;
        } else { sc[j] = 0.f; sh[j] = 0.f; }
    }

    const float* Kt = ws + WS_KT;
    float4 rx = make_float4(0.f,0.f,0.f,0.f);
    float4 rk0, rk1;

    // ---- prefetch chunk 0 ----
    {
        if (sx_on) {
            const float* xp = &x[((size_t)b*SEQ + sx_t)*ENC];
            int e = e0 + sx_e;
            if (e + 3 < ENC) { float4 v = *(const float4*)&xp[e];
                rx.x=v.x*sc[0]+sh[0]; rx.y=v.y*sc[1]+sh[1]; rx.z=v.z*sc[2]+sh[2]; rx.w=v.w*sc[3]+sh[3]; }
            else {
                float v0 = (e   < ENC) ? xp[e]   : 0.f;
                float v1 = (e+1 < ENC) ? xp[e+1] : 0.f;
                float v2 = (e+2 < ENC) ? xp[e+2] : 0.f;
                float v3 = (e+3 < ENC) ? xp[e+3] : 0.f;
                rx.x=v0*sc[0]+sh[0]; rx.y=v1*sc[1]+sh[1]; rx.z=v2*sc[2]+sh[2]; rx.w=v3*sc[3]+sh[3];
            }
        }
        const float* Kp = Kt;                       // ch=0
        rk0 = *(const float4*)&Kp[tid*4];
        if (tid < 448) rk1 = *(const float4*)&Kp[2048 + tid*4];
    }
    if (sx_on) *(float4*)&xt[0][sx_t*ETILE + sx_e] = rx;
    *(float4*)&Ks[0][tid*4] = rk0;
    if (tid < 448) *(float4*)&Ks[0][2048 + tid*4] = rk1;

    // compute role: wave w owns e = e0 + w*4 .. +3, m = lane
    const int m  = tid & 63;
    const int eI = tid >> 6;   // wave-uniform
    float acc[4] = {0.f, 0.f, 0.f, 0.f};

    for (int ch = 0; ch < NCH; ch++) {
        // issue next chunk's global loads (in flight across the barrier + compute)
        if (ch + 1 < NCH) {
            if (sx_on) {
                const float* xp = &x[((size_t)b*SEQ + (ch+1)*TCH + sx_t)*ENC];
                int e = e0 + sx_e;
                if (e + 3 < ENC) { float4 v = *(const float4*)&xp[e];
                    rx.x=v.x*sc[0]+sh[0]; rx.y=v.y*sc[1]+sh[1]; rx.z=v.z*sc[2]+sh[2]; rx.w=v.w*sc[3]+sh[3]; }
                else {
                    float v0 = (e   < ENC) ? xp[e]   : 0.f;
                    float v1 = (e+1 < ENC) ? xp[e+1] : 0.f;
                    float v2 = (e+2 < ENC) ? xp[e+2] : 0.f;
                    float v3 = (e+3 < ENC) ? xp[e+3] : 0.f;
                    rx.x=v0*sc[0]+sh[0]; rx.y=v1*sc[1]+sh[1]; rx.z=v2*sc[2]+sh[2]; rx.w=v3*sc[3]+sh[3];
                }
            }
            const float* Kp = Kt + (size_t)(ch+1)*TCH*64;
            rk0 = *(const float4*)&Kp[tid*4];
            if (tid < 448) rk1 = *(const float4*)&Kp[2048 + tid*4];
        }
        __syncthreads();   // buf[ch&1] fully written; prev compute done
        const float* xb = xt[ch & 1];
        const float* kb = Ks[ch & 1];
        #pragma unroll 10
        for (int tt = 0; tt < TCH; tt++) {
            float4 f = *(const float4*)&xb[tt*ETILE + eI*4];   // wave-broadcast
            float kv = kb[tt*64 + m];                          // 2-way bank alias: free
            acc[0] += f.x*kv; acc[1] += f.y*kv; acc[2] += f.z*kv; acc[3] += f.w*kv;
        }
        if (ch + 1 < NCH) {
            if (sx_on) *(float4*)&xt[(ch+1)&1][sx_t*ETILE + sx_e] = rx;
            *(float4*)&Ks[(ch+1)&1][tid*4] = rk0;
            if (tid < 448) *(float4*)&Ks[(ch+1)&1][2048 + tid*4] = rk1;
        }
    }

    float* C = ws + WS_C;
    #pragma unroll
    for (int j = 0; j < 4; j++) {
        int e = e0 + eI*4 + j;
        if (e < ENC) C[(size_t)(b*ENC + e)*64 + m] = acc[j];   // coalesced, no atomics
    }
}

// ---------------- Kernel 3: out = C @ EW^T + evb, then denorm ----------------
// grid 16b x 12 t'-tiles(64) x 6 e-tiles(64); 256 thr; FULL unroll (no creg spill).
__global__ __launch_bounds__(256) void k3(const float* __restrict__ aw,
        const float* __restrict__ ab, const float* __restrict__ ws,
        float* __restrict__ out)
{
    __shared__ float EWt[64*68];   // [m][t'] transposed, pad 68
    __shared__ float Ct[64*68];    // [el][m], pad 68
    const int tid = threadIdx.x;
    const int bid = blockIdx.x;
    const int b   = bid / 72;
    const int r   = bid % 72;
    const int tt0 = (r / 6) * 64;
    const int e0  = (r % 6) * 64;
    const int lane = tid & 63;
    const int tq   = tid >> 6;
    {
        const float* EW = ws + WS_EW;
        #pragma unroll
        for (int i = 0; i < 16; i++) {
            int tl = tq*16 + i;
            int tp = tt0 + tl;
            float v = (tp < PRED) ? EW[(size_t)tp*64 + lane] : 0.f;
            EWt[lane*68 + tl] = v;
        }
        const float* C = ws + WS_C + (size_t)(b*ENC + e0)*64;
        #pragma unroll
        for (int k = 0; k < 16; k++) {
            int idx = k*256 + tid;
            int el = idx >> 6, mm = idx & 63;
            float v = (e0 + el < ENC) ? C[idx] : 0.f;
            Ct[el*68 + mm] = v;
        }
    }
    __syncthreads();
    const int e = e0 + lane;
    const bool valid = e < ENC;
    const int p = b*ENC + e;
    float creg[64];
    #pragma unroll
    for (int k = 0; k < 16; k++) {
        float4 v = *(const float4*)&Ct[lane*68 + 4*k];
        creg[4*k]=v.x; creg[4*k+1]=v.y; creg[4*k+2]=v.z; creg[4*k+3]=v.w;
    }
    float acc[16];
    #pragma unroll
    for (int i = 0; i < 16; i++) acc[i] = 0.f;
    #pragma unroll   // FULL unroll: creg indices become compile-time constants (no scratch spill)
    for (int mI = 0; mI < 64; mI++) {
        const float* wr = &EWt[mI*68 + tq*16];
        float4 w0 = *(const float4*)&wr[0];
        float4 w1 = *(const float4*)&wr[4];
        float4 w2 = *(const float4*)&wr[8];
        float4 w3 = *(const float4*)&wr[12];
        float c = creg[mI];
        acc[0]+=w0.x*c; acc[1]+=w0.y*c; acc[2]+=w0.z*c; acc[3]+=w0.w*c;
        acc[4]+=w1.x*c; acc[5]+=w1.y*c; acc[6]+=w1.z*c; acc[7]+=w1.w*c;
        acc[8]+=w2.x*c; acc[9]+=w2.y*c; acc[10]+=w2.z*c; acc[11]+=w2.w*c;
        acc[12]+=w3.x*c; acc[13]+=w3.y*c; acc[14]+=w3.z*c; acc[15]+=w3.w*c;
    }
    float mean=0.f, sd=0.f, iaw=0.f, abe=0.f;
    if (valid) {
        mean = ws[WS_MEAN + p];
        sd   = ws[WS_STDEV + p];
        iaw  = 1.0f/(aw[e] + 1e-10f);
        abe  = ab[e];
    }
    const float* evb = ws + WS_EVB;
    #pragma unroll
    for (int i = 0; i < 16; i++) {
        int tp = tt0 + tq*16 + i;
        if (valid && tp < PRED) {
            float v = (acc[i] + evb[tp] - abe) * iaw * sd + mean;
            out[((size_t)b*PRED + tp)*ENC + e] = v;
        }
    }
}

extern "C" void kernel_launch(void* const* d_in, const int* in_sizes, int n_in,
                              void* d_out, int out_size, void* d_ws, size_t ws_size,
                              hipStream_t stream)
{
    const float* x     = (const float*)d_in[0];
    const float* A     = (const float*)d_in[1];
    const float* Bv    = (const float*)d_in[2];
    const float* evalm = (const float*)d_in[3];
    const float* W     = (const float*)d_in[4];
    const float* bm    = (const float*)d_in[5];
    const float* aw    = (const float*)d_in[6];
    const float* ab    = (const float*)d_in[7];
    float* ws  = (float*)d_ws;
    float* out = (float*)d_out;

    const size_t smbytes = (size_t)(256*64 + 2*64*68) * sizeof(float); // 100352 B
    hipFuncSetAttribute((const void*)k1, hipFuncAttributeMaxDynamicSharedMemorySize, (int)smbytes);

    k1<<<NSTATS + NEWB + 1, 1024, smbytes, stream>>>(x, A, Bv, evalm, W, bm, ws);
    k2<<<BATCH*11, 512, 0, stream>>>(x, aw, ab, ws);
    k3<<<1152, 256, 0, stream>>>(aw, ab, ws, out);
}

// Round 4
// 208.706 us; speedup vs baseline: 5.1345x; 5.1345x over previous
//
#include <hip/hip_runtime.h>
#include <math.h>

#define BATCH 16
#define SEQ   720
#define ENC   321
#define NORD  64
#define PRED  720
#define NPAIR (BATCH*ENC)   // 5136

// workspace layout (float offsets)
#define WS_MEAN   0
#define WS_RSTD   (WS_MEAN + NPAIR)        // 5136
#define WS_STDEV  (WS_RSTD + NPAIR)        // 10272
#define WS_KT     (WS_STDEV + NPAIR)       // 15408  (720x64, t-major: K[t][m] = (A^(719-t) B)[m])
#define WS_EW     (WS_KT + PRED*NORD)      // 61488  (720x64: EW[t'][m] = sum_n eval[t'][n] W[n][m])
#define WS_EVB    (WS_EW + PRED*NORD)      // 107568 (720: eval[t']·b_mlp)
#define WS_C      (WS_EVB + PRED)          // 108288 (5136x64: c_final per pair)

// ---------------- k1a: RevIN stats (96 blocks) ----------------
__global__ __launch_bounds__(1024) void k1a(const float* __restrict__ x,
        float* __restrict__ ws)
{
    __shared__ float r1[1024], r2[1024];
    const int tid  = threadIdx.x;
    const int lane = tid & 63;
    const int wv   = tid >> 6;
    const int b = blockIdx.x / 6, et = blockIdx.x % 6;
    const int e = et*64 + lane;
    const bool valid = e < ENC;
    float sum = 0.f, ss = 0.f;
    if (valid) {
        const float* xp = x + (size_t)b*SEQ*ENC + e;
        for (int t = wv; t < SEQ; t += 16) {
            float v = xp[(size_t)t*ENC];
            sum += v; ss += v*v;
        }
    }
    r1[wv*64+lane] = sum; r2[wv*64+lane] = ss;
    __syncthreads();
    if (wv == 0 && valid) {
        float s = 0.f, q = 0.f;
        #pragma unroll
        for (int k = 0; k < 16; k++) { s += r1[k*64+lane]; q += r2[k*64+lane]; }
        float mean = s * (1.0f/SEQ);
        float var  = q * (1.0f/SEQ) - mean*mean;
        float sd   = sqrtf(var + 1e-5f);
        int p = b*ENC + e;
        ws[WS_MEAN  + p] = mean;
        ws[WS_STDEV + p] = sd;
        ws[WS_RSTD  + p] = 1.0f / sd;
    }
}

// ---------------- k1b: EW = eval @ W, evb = eval @ b  (12 blocks) ----------------
__global__ __launch_bounds__(1024) void k1b(const float* __restrict__ evalm,
        const float* __restrict__ W, const float* __restrict__ bm,
        float* __restrict__ ws)
{
    __shared__ float sm[64*65];
    const int tid  = threadIdx.x;
    const int lane = tid & 63;
    const int wv   = tid >> 6;
    const int r = blockIdx.x;
    for (int idx = tid; idx < 64*64; idx += 1024) {
        int n = idx >> 6, m = idx & 63;
        sm[n*65 + m] = W[idx];
    }
    __syncthreads();
    float bv = bm[lane];
    #pragma unroll
    for (int k = 0; k < 4; k++) {
        int row = wv + k*16;
        if (row < 60) {
            int tp = r*60 + row;
            const float* ev = evalm + (size_t)tp*64;
            float acc = 0.f;
            #pragma unroll
            for (int kk = 0; kk < 16; kk++) {
                float4 e4 = *(const float4*)&ev[4*kk];
                acc += e4.x*sm[(4*kk+0)*65+lane] + e4.y*sm[(4*kk+1)*65+lane]
                     + e4.z*sm[(4*kk+2)*65+lane] + e4.w*sm[(4*kk+3)*65+lane];
            }
            ws[WS_EW + (size_t)tp*64 + lane] = acc;
            float pv = ev[lane] * bv;
            #pragma unroll
            for (int o = 32; o > 0; o >>= 1) pv += __shfl_down(pv, o);
            if (lane == 0) ws[WS_EVB + tp] = pv;
        }
    }
}

// ---------------- k1c: Krylov build K[j] = A^j B by doubling (1 block) ----------------
__global__ __launch_bounds__(1024) void k1c(const float* __restrict__ A,
        const float* __restrict__ Bv, float* __restrict__ ws)
{
    extern __shared__ float sm[];
    const int tid  = threadIdx.x;
    const int lane = tid & 63;
    const int wv   = tid >> 6;
    float* Kl  = sm;                    // [256][64] rows j=0..255 (only these re-read)
    float* Ap  = sm + 256*64;           // [64][68]  A^m
    float* ApT = Ap + 64*68;            // [64][68]  (A^m)^T
    float* Kt  = ws + WS_KT;
    for (int idx = tid; idx < 64*64; idx += 1024) {
        int n = idx >> 6, m = idx & 63;
        float v = A[idx];
        Ap[n*68+m] = v; ApT[m*68+n] = v;
    }
    if (tid < 64) {
        float bv = Bv[tid];
        Kl[tid] = bv;
        Kt[(size_t)719*64 + tid] = bv;
    }
    __syncthreads();
    float ar[64];                        // register cache: row `lane` of A^m
    #pragma unroll
    for (int k = 0; k < 16; k++) {
        float4 v = *(const float4*)&Ap[lane*68 + 4*k];
        ar[4*k]=v.x; ar[4*k+1]=v.y; ar[4*k+2]=v.z; ar[4*k+3]=v.w;
    }
    int m = 1;
    while (m < 720) {
        const int hi = (2*m < 720) ? 2*m : 720;
        for (int j2 = m + wv; j2 < hi; j2 += 16) {
            const float* src = &Kl[(j2 - m)*64];
            float acc = 0.f;
            #pragma unroll
            for (int k = 0; k < 16; k++) {
                float4 s = *(const float4*)&src[4*k];  // wave-uniform broadcast
                acc += ar[4*k]*s.x + ar[4*k+1]*s.y + ar[4*k+2]*s.z + ar[4*k+3]*s.w;
            }
            if (j2 < 256) Kl[j2*64 + lane] = acc;
            Kt[(size_t)(719 - j2)*64 + lane] = acc;
        }
        const bool sq = (hi < 720);
        float nacc[4];
        if (sq) {
            #pragma unroll
            for (int q = 0; q < 4; q++) {
                int c = wv*4 + q;
                const float* src = &ApT[c*68];
                float acc = 0.f;
                #pragma unroll
                for (int k = 0; k < 16; k++) {
                    float4 s = *(const float4*)&src[4*k];
                    acc += ar[4*k]*s.x + ar[4*k+1]*s.y + ar[4*k+2]*s.z + ar[4*k+3]*s.w;
                }
                nacc[q] = acc;
            }
        }
        __syncthreads();
        if (sq) {
            #pragma unroll
            for (int q = 0; q < 4; q++) {
                int c = wv*4 + q;
                Ap[lane*68 + c]  = nacc[q];
                ApT[c*68 + lane] = nacc[q];
            }
        }
        __syncthreads();
        if (sq) {
            #pragma unroll
            for (int k = 0; k < 16; k++) {
                float4 v = *(const float4*)&Ap[lane*68 + 4*k];
                ar[4*k]=v.x; ar[4*k+1]=v.y; ar[4*k+2]=v.z; ar[4*k+3]=v.w;
            }
        }
        m = hi;
    }
}

// ---------------- k2: C[p][m] = sum_t f[p][t] * K[t][m]  (no atomics) ----------------
#define ETILE 32
#define TCH   60
#define NCH   12
__global__ __launch_bounds__(512) void k2(const float* __restrict__ x,
        const float* __restrict__ aw, const float* __restrict__ ab,
        float* __restrict__ ws)
{
    __shared__ float xt[2][TCH*ETILE];   // f tile [tt][ee], scale/shift pre-applied
    __shared__ float Ks[2][TCH*64];      // K tile [tt][m]
    const int tid = threadIdx.x;
    const int b   = blockIdx.x / 11;
    const int et  = blockIdx.x % 11;
    const int e0  = et*ETILE;

    const int  sx_t  = tid >> 3;            // 0..63 (used if <60)
    const int  sx_e  = (tid & 7) * 4;
    const bool sx_on = tid < 480;           // 480 = 60*32/4

    float sc[4], sh[4];
    #pragma unroll
    for (int j = 0; j < 4; j++) {
        int e = e0 + sx_e + j;
        if (e < ENC) {
            int p = b*ENC + e;
            float rs = ws[WS_RSTD + p];
            float mn = ws[WS_MEAN + p];
            float a  = aw[e];
            sc[j] = rs * a;
            sh[j] = ab[e] - mn * rs * a;
        } else { sc[j] = 0.f; sh[j] = 0.f; }
    }

    const float* Kt = ws + WS_KT;
    float4 rx = make_float4(0.f,0.f,0.f,0.f);
    float4 rk0, rk1;

    {
        if (sx_on) {
            const float* xp = &x[((size_t)b*SEQ + sx_t)*ENC];
            int e = e0 + sx_e;
            if (e + 3 < ENC) { float4 v = *(const float4*)&xp[e];
                rx.x=v.x*sc[0]+sh[0]; rx.y=v.y*sc[1]+sh[1]; rx.z=v.z*sc[2]+sh[2]; rx.w=v.w*sc[3]+sh[3]; }
            else {
                float v0 = (e   < ENC) ? xp[e]   : 0.f;
                float v1 = (e+1 < ENC) ? xp[e+1] : 0.f;
                float v2 = (e+2 < ENC) ? xp[e+2] : 0.f;
                float v3 = (e+3 < ENC) ? xp[e+3] : 0.f;
                rx.x=v0*sc[0]+sh[0]; rx.y=v1*sc[1]+sh[1]; rx.z=v2*sc[2]+sh[2]; rx.w=v3*sc[3]+sh[3];
            }
        }
        rk0 = *(const float4*)&Kt[tid*4];
        if (tid < 448) rk1 = *(const float4*)&Kt[2048 + tid*4];
    }
    if (sx_on) *(float4*)&xt[0][sx_t*ETILE + sx_e] = rx;
    *(float4*)&Ks[0][tid*4] = rk0;
    if (tid < 448) *(float4*)&Ks[0][2048 + tid*4] = rk1;

    const int m  = tid & 63;
    const int eI = tid >> 6;   // wave-uniform
    float acc[4] = {0.f, 0.f, 0.f, 0.f};

    for (int ch = 0; ch < NCH; ch++) {
        if (ch + 1 < NCH) {
            if (sx_on) {
                const float* xp = &x[((size_t)b*SEQ + (ch+1)*TCH + sx_t)*ENC];
                int e = e0 + sx_e;
                if (e + 3 < ENC) { float4 v = *(const float4*)&xp[e];
                    rx.x=v.x*sc[0]+sh[0]; rx.y=v.y*sc[1]+sh[1]; rx.z=v.z*sc[2]+sh[2]; rx.w=v.w*sc[3]+sh[3]; }
                else {
                    float v0 = (e   < ENC) ? xp[e]   : 0.f;
                    float v1 = (e+1 < ENC) ? xp[e+1] : 0.f;
                    float v2 = (e+2 < ENC) ? xp[e+2] : 0.f;
                    float v3 = (e+3 < ENC) ? xp[e+3] : 0.f;
                    rx.x=v0*sc[0]+sh[0]; rx.y=v1*sc[1]+sh[1]; rx.z=v2*sc[2]+sh[2]; rx.w=v3*sc[3]+sh[3];
                }
            }
            const float* Kp = Kt + (size_t)(ch+1)*TCH*64;
            rk0 = *(const float4*)&Kp[tid*4];
            if (tid < 448) rk1 = *(const float4*)&Kp[2048 + tid*4];
        }
        __syncthreads();
        const float* xb = xt[ch & 1];
        const float* kb = Ks[ch & 1];
        #pragma unroll 10
        for (int tt = 0; tt < TCH; tt++) {
            float4 f = *(const float4*)&xb[tt*ETILE + eI*4];   // wave-broadcast
            float kv = kb[tt*64 + m];                          // 2-way bank alias: free
            acc[0] += f.x*kv; acc[1] += f.y*kv; acc[2] += f.z*kv; acc[3] += f.w*kv;
        }
        if (ch + 1 < NCH) {
            if (sx_on) *(float4*)&xt[(ch+1)&1][sx_t*ETILE + sx_e] = rx;
            *(float4*)&Ks[(ch+1)&1][tid*4] = rk0;
            if (tid < 448) *(float4*)&Ks[(ch+1)&1][2048 + tid*4] = rk1;
        }
    }

    float* C = ws + WS_C;
    #pragma unroll
    for (int j = 0; j < 4; j++) {
        int e = e0 + eI*4 + j;
        if (e < ENC) C[(size_t)(b*ENC + e)*64 + m] = acc[j];   // coalesced, no atomics
    }
}

// ---------------- k3: out = C @ EW^T + evb, denorm — bounded registers ----------------
// grid 16b x 12 t'-tiles(64) x 6 e-tiles(64); 256 thr.
// NO creg[] register array (R3 post-mortem: 256 VGPR + 1.7 GB scratch thrash).
// cv read from LDS per m (pad 65 -> conflict-free), EWt reads are wave-broadcast.
__global__ __launch_bounds__(256) void k3(const float* __restrict__ aw,
        const float* __restrict__ ab, const float* __restrict__ ws,
        float* __restrict__ out)
{
    __shared__ float EWt[64*68];   // [m][t'] transposed, pad 68 (16B-aligned rows)
    __shared__ float Ct[64*65];    // [el][m], pad 65 (conflict-free per-lane column reads)
    const int tid = threadIdx.x;
    const int bid = blockIdx.x;
    const int b   = bid / 72;
    const int r   = bid % 72;
    const int tt0 = (r / 6) * 64;
    const int e0  = (r % 6) * 64;
    const int lane = tid & 63;
    const int tq   = tid >> 6;
    {
        const float* EW = ws + WS_EW;
        #pragma unroll
        for (int i = 0; i < 16; i++) {
            int tl = tq*16 + i;
            EWt[lane*68 + tl] = EW[(size_t)(tt0 + tl)*64 + lane];
        }
        const float* C = ws + WS_C + (size_t)(b*ENC + e0)*64;
        #pragma unroll
        for (int k = 0; k < 16; k++) {
            int idx = k*256 + tid;
            int el = idx >> 6, mm = idx & 63;
            float v = (e0 + el < ENC) ? C[idx] : 0.f;
            Ct[el*65 + mm] = v;
        }
    }
    __syncthreads();
    const int e = e0 + lane;
    const bool valid = e < ENC;
    const int p = b*ENC + e;

    float acc[16];
    #pragma unroll
    for (int i = 0; i < 16; i++) acc[i] = 0.f;
    #pragma unroll 4
    for (int m = 0; m < 64; m++) {
        float cv = Ct[lane*65 + m];                 // bank (lane+m)%32: conflict-free
        const float* wr = &EWt[m*68 + tq*16];       // wave-uniform: broadcast
        float4 w0 = *(const float4*)&wr[0];
        float4 w1 = *(const float4*)&wr[4];
        float4 w2 = *(const float4*)&wr[8];
        float4 w3 = *(const float4*)&wr[12];
        acc[0]+=w0.x*cv; acc[1]+=w0.y*cv; acc[2]+=w0.z*cv; acc[3]+=w0.w*cv;
        acc[4]+=w1.x*cv; acc[5]+=w1.y*cv; acc[6]+=w1.z*cv; acc[7]+=w1.w*cv;
        acc[8]+=w2.x*cv; acc[9]+=w2.y*cv; acc[10]+=w2.z*cv; acc[11]+=w2.w*cv;
        acc[12]+=w3.x*cv; acc[13]+=w3.y*cv; acc[14]+=w3.z*cv; acc[15]+=w3.w*cv;
    }
    float mean=0.f, sd=0.f, iaw=0.f, abe=0.f;
    if (valid) {
        mean = ws[WS_MEAN + p];
        sd   = ws[WS_STDEV + p];
        iaw  = 1.0f/(aw[e] + 1e-10f);
        abe  = ab[e];
    }
    const float* evb = ws + WS_EVB;
    #pragma unroll
    for (int i = 0; i < 16; i++) {
        int tp = tt0 + tq*16 + i;
        if (valid && tp < PRED) {
            float v = (acc[i] + evb[tp] - abe) * iaw * sd + mean;
            out[((size_t)b*PRED + tp)*ENC + e] = v;
        }
    }
}

extern "C" void kernel_launch(void* const* d_in, const int* in_sizes, int n_in,
                              void* d_out, int out_size, void* d_ws, size_t ws_size,
                              hipStream_t stream)
{
    const float* x     = (const float*)d_in[0];
    const float* A     = (const float*)d_in[1];
    const float* Bv    = (const float*)d_in[2];
    const float* evalm = (const float*)d_in[3];
    const float* W     = (const float*)d_in[4];
    const float* bm    = (const float*)d_in[5];
    const float* aw    = (const float*)d_in[6];
    const float* ab    = (const float*)d_in[7];
    float* ws  = (float*)d_ws;
    float* out = (float*)d_out;

    const size_t smbytes = (size_t)(256*64 + 2*64*68) * sizeof(float); // 100352 B
    hipFuncSetAttribute((const void*)k1c, hipFuncAttributeMaxDynamicSharedMemorySize, (int)smbytes);

    k1a<<<96, 1024, 0, stream>>>(x, ws);
    k1b<<<12, 1024, 0, stream>>>(evalm, W, bm, ws);
    k1c<<<1, 1024, smbytes, stream>>>(A, Bv, ws);
    k2 <<<BATCH*11, 512, 0, stream>>>(x, aw, ab, ws);
    k3 <<<1152, 256, 0, stream>>>(aw, ab, ws, out);
}

// Round 6
// 180.788 us; speedup vs baseline: 5.9274x; 1.1544x over previous
//
#include <hip/hip_runtime.h>
#include <math.h>

#define BATCH 16
#define SEQ   720
#define ENC   321
#define NORD  64
#define PRED  720
#define NPAIR (BATCH*ENC)   // 5136

// ---- workspace layout (float offsets), ~1.75 MB total ----
#define WS_MEAN   0
#define WS_STDEV  (WS_MEAN + NPAIR)        // 5136
#define WS_KT     (WS_STDEV + NPAIR)       // 10272  (720x64, Kt[t][m] = (A^(719-t) B)[m])
#define WS_EW     (WS_KT + PRED*NORD)      // 56352  (720x64)
#define WS_EVB    (WS_EW + PRED*NORD)      // 102432 (720)
#define WS_C      (WS_EVB + PRED)          // 103152 (5136x64)
#define WS_A16    (WS_C + NPAIR*NORD)      // 431856 (64x64 = A^16)

// ---- d_out used as scratch before k3 writes it (out_size = 3,699,360 floats) ----
#define GB_G      0                         // 4 slabs x 96 tiles x 4096 = 1,572,864
#define GB_PS_SUM 1572864                   // 4*16*6*64 = 24576
#define GB_PS_SS  (GB_PS_SUM + 24576)       // ends 1,622,016 < 3,699,360

// ---------------- k1b: EW = eval @ W, evb = eval @ b  (12 blocks) ----------------
__global__ __launch_bounds__(1024) void k1b(const float* __restrict__ evalm,
        const float* __restrict__ W, const float* __restrict__ bm,
        float* __restrict__ ws)
{
    __shared__ float sm[64*65];
    const int tid  = threadIdx.x;
    const int lane = tid & 63;
    const int wv   = tid >> 6;
    const int r = blockIdx.x;
    for (int idx = tid; idx < 64*64; idx += 1024) {
        int n = idx >> 6, m = idx & 63;
        sm[n*65 + m] = W[idx];
    }
    __syncthreads();
    float bv = bm[lane];
    #pragma unroll
    for (int k = 0; k < 4; k++) {
        int row = wv + k*16;
        if (row < 60) {
            int tp = r*60 + row;
            const float* ev = evalm + (size_t)tp*64;
            float acc = 0.f;
            #pragma unroll
            for (int kk = 0; kk < 16; kk++) {
                float4 e4 = *(const float4*)&ev[4*kk];
                acc += e4.x*sm[(4*kk+0)*65+lane] + e4.y*sm[(4*kk+1)*65+lane]
                     + e4.z*sm[(4*kk+2)*65+lane] + e4.w*sm[(4*kk+3)*65+lane];
            }
            ws[WS_EW + (size_t)tp*64 + lane] = acc;
            float pv = ev[lane] * bv;
            #pragma unroll
            for (int o = 32; o > 0; o >>= 1) pv += __shfl_down(pv, o);
            if (lane == 0) ws[WS_EVB + tp] = pv;
        }
    }
}

// ---------------- p1: A^2..A^16 by squaring + K rows 0..15 (1 block) ----------------
__global__ __launch_bounds__(1024) void p1(const float* __restrict__ A,
        const float* __restrict__ Bv, float* __restrict__ ws)
{
    __shared__ float Kl[16*64];
    __shared__ float Ap[64*68];
    __shared__ float ApT[64*68];
    const int tid  = threadIdx.x;
    const int lane = tid & 63;
    const int wv   = tid >> 6;
    float* Kt = ws + WS_KT;
    for (int idx = tid; idx < 64*64; idx += 1024) {
        int n = idx >> 6, m = idx & 63;
        float v = A[idx];
        Ap[n*68+m] = v; ApT[m*68+n] = v;
    }
    if (tid < 64) {
        float bv = Bv[tid];
        Kl[tid] = bv;
        Kt[(size_t)719*64 + tid] = bv;
    }
    __syncthreads();
    float ar[64];                        // row `lane` of A^m
    #pragma unroll
    for (int k = 0; k < 16; k++) {
        float4 v = *(const float4*)&Ap[lane*68 + 4*k];
        ar[4*k]=v.x; ar[4*k+1]=v.y; ar[4*k+2]=v.z; ar[4*k+3]=v.w;
    }
    int m = 1;
    while (m < 16) {
        const int hi = 2*m;
        // expand rows m..hi-1:  K[j2] = A^m @ K[j2-m]
        for (int j2 = m + wv; j2 < hi; j2 += 16) {
            const float* src = &Kl[(j2 - m)*64];
            float acc = 0.f;
            #pragma unroll
            for (int k = 0; k < 16; k++) {
                float4 s = *(const float4*)&src[4*k];
                acc += ar[4*k]*s.x + ar[4*k+1]*s.y + ar[4*k+2]*s.z + ar[4*k+3]*s.w;
            }
            Kl[j2*64 + lane] = acc;
            Kt[(size_t)(719 - j2)*64 + lane] = acc;
        }
        // square: Anew = A^m @ A^m
        float nacc[4];
        #pragma unroll
        for (int q = 0; q < 4; q++) {
            int c = wv*4 + q;
            const float* src = &ApT[c*68];
            float acc = 0.f;
            #pragma unroll
            for (int k = 0; k < 16; k++) {
                float4 s = *(const float4*)&src[4*k];
                acc += ar[4*k]*s.x + ar[4*k+1]*s.y + ar[4*k+2]*s.z + ar[4*k+3]*s.w;
            }
            nacc[q] = acc;
        }
        __syncthreads();
        #pragma unroll
        for (int q = 0; q < 4; q++) {
            int c = wv*4 + q;
            Ap[lane*68 + c]  = nacc[q];
            ApT[c*68 + lane] = nacc[q];
        }
        __syncthreads();
        #pragma unroll
        for (int k = 0; k < 16; k++) {
            float4 v = *(const float4*)&Ap[lane*68 + 4*k];
            ar[4*k]=v.x; ar[4*k+1]=v.y; ar[4*k+2]=v.z; ar[4*k+3]=v.w;
        }
        m = hi;
    }
    // Ap now holds A^16
    for (int idx = tid; idx < 64*64; idx += 1024)
        ws[WS_A16 + idx] = Ap[(idx>>6)*68 + (idx&63)];
}

// ---------------- p2: 16 parallel chains K[r+16q] = A^16 K[r+16(q-1)] ----------------
// 8 blocks x 128 thr (2 waves = 2 chains/block), A^16 row in registers.
__global__ __launch_bounds__(128) void p2(float* __restrict__ ws)
{
    __shared__ float sv[2][64];
    const int lane = threadIdx.x & 63;
    const int wv   = threadIdx.x >> 6;
    const int r    = blockIdx.x*2 + wv;          // chain id 0..15
    const float* A16 = ws + WS_A16;
    float* Kt = ws + WS_KT;
    float ar16[64];
    #pragma unroll
    for (int k = 0; k < 16; k++) {
        float4 v = *(const float4*)&A16[lane*64 + 4*k];
        ar16[4*k]=v.x; ar16[4*k+1]=v.y; ar16[4*k+2]=v.z; ar16[4*k+3]=v.w;
    }
    sv[wv][lane] = Kt[(size_t)(719 - r)*64 + lane];   // seed K[r]
    for (int q = 1; q <= 44; q++) {
        const int j = r + 16*q;                       // <= 719
        float acc = 0.f;
        #pragma unroll
        for (int k = 0; k < 16; k++) {
            float4 v = *(const float4*)&sv[wv][4*k];
            acc += ar16[4*k]*v.x + ar16[4*k+1]*v.y + ar16[4*k+2]*v.z + ar16[4*k+3]*v.w;
        }
        sv[wv][lane] = acc;                           // same-wave DS ordering
        Kt[(size_t)(719 - j)*64 + lane] = acc;
    }
}

// ---------------- k2: G[p][m] = sum_t x[p][t] K[t][m] + stats partials ----------------
// grid 16b x 6 et(64) x 4 tsplit = 384 blocks, 256 thr; no atomics; G slabs in d_out.
__device__ inline float4 ldx(const float* __restrict__ x, int b, int t, int e4)
{
    float4 r = make_float4(0.f,0.f,0.f,0.f);
    const float* p = x + ((size_t)b*SEQ + t)*ENC;
    if (e4 + 3 < ENC) r = *(const float4*)&p[e4];
    else {
        if (e4   < ENC) r.x = p[e4];
        if (e4+1 < ENC) r.y = p[e4+1];
        if (e4+2 < ENC) r.z = p[e4+2];
    }
    return r;
}

__global__ __launch_bounds__(256) void k2(const float* __restrict__ x,
        float* __restrict__ gbuf, const float* __restrict__ ws)
{
    __shared__ float xt[2][12*64];
    __shared__ float ks[2][12*64];
    __shared__ float redn[12*64];
    __shared__ float reds[12*64];
    const int tid = threadIdx.x;
    const int bid = blockIdx.x;
    const int b = bid / 24, rem = bid % 24;
    const int et = rem / 4, tsp = rem % 4;
    const int e0 = et*64, t0 = tsp*180;

    const bool xon = tid < 192;
    const bool kon = tid >= 64;
    const int sx_t  = tid >> 4;          // 0..11 (x loader)
    const int sx_e4 = (tid & 15) * 4;
    const int sk    = tid - 64;          // 0..191 (K loader)
    const int sk_t  = sk >> 4;
    const int sk_m4 = (sk & 15) * 4;

    const float* Kt = ws + WS_KT;
    float s0=0,s1=0,s2=0,s3=0, q0=0,q1=0,q2=0,q3=0;
    float4 rx = make_float4(0,0,0,0), rk = make_float4(0,0,0,0);

    if (xon) rx = ldx(x, b, t0 + sx_t, e0 + sx_e4);
    if (kon) rk = *(const float4*)&Kt[(size_t)(t0 + sk_t)*64 + sk_m4];
    if (xon) {
        *(float4*)&xt[0][sx_t*64 + sx_e4] = rx;
        s0+=rx.x; s1+=rx.y; s2+=rx.z; s3+=rx.w;
        q0+=rx.x*rx.x; q1+=rx.y*rx.y; q2+=rx.z*rx.z; q3+=rx.w*rx.w;
    }
    if (kon) *(float4*)&ks[0][sk_t*64 + sk_m4] = rk;

    const int lane = tid & 63, wv = tid >> 6;
    const int mg = lane & 15, eg = lane >> 4;
    const int eoff = wv*16 + eg*4;       // local e base (block covers 64 e)
    float acc[4][4];
    #pragma unroll
    for (int j = 0; j < 4; j++)
        #pragma unroll
        for (int i = 0; i < 4; i++) acc[j][i] = 0.f;

    for (int ch = 0; ch < 15; ch++) {
        if (ch + 1 < 15) {
            if (xon) rx = ldx(x, b, t0 + (ch+1)*12 + sx_t, e0 + sx_e4);
            if (kon) rk = *(const float4*)&Kt[(size_t)(t0 + (ch+1)*12 + sk_t)*64 + sk_m4];
        }
        __syncthreads();
        const float* xb = xt[ch & 1];
        const float* kb = ks[ch & 1];
        #pragma unroll
        for (int tt = 0; tt < 12; tt++) {
            float4 f  = *(const float4*)&xb[tt*64 + eoff];
            float4 kv = *(const float4*)&kb[tt*64 + mg*4];
            acc[0][0]+=f.x*kv.x; acc[0][1]+=f.x*kv.y; acc[0][2]+=f.x*kv.z; acc[0][3]+=f.x*kv.w;
            acc[1][0]+=f.y*kv.x; acc[1][1]+=f.y*kv.y; acc[1][2]+=f.y*kv.z; acc[1][3]+=f.y*kv.w;
            acc[2][0]+=f.z*kv.x; acc[2][1]+=f.z*kv.y; acc[2][2]+=f.z*kv.z; acc[2][3]+=f.z*kv.w;
            acc[3][0]+=f.w*kv.x; acc[3][1]+=f.w*kv.y; acc[3][2]+=f.w*kv.z; acc[3][3]+=f.w*kv.w;
        }
        if (ch + 1 < 15) {
            if (xon) {
                *(float4*)&xt[(ch+1)&1][sx_t*64 + sx_e4] = rx;
                s0+=rx.x; s1+=rx.y; s2+=rx.z; s3+=rx.w;
                q0+=rx.x*rx.x; q1+=rx.y*rx.y; q2+=rx.z*rx.z; q3+=rx.w*rx.w;
            }
            if (kon) *(float4*)&ks[(ch+1)&1][sk_t*64 + sk_m4] = rk;
        }
    }

    // G slab write (coalesced, no atomics)
    float* g = gbuf + GB_G + (size_t)(tsp*96 + b*6 + et)*4096;
    #pragma unroll
    for (int j = 0; j < 4; j++)
        *(float4*)&g[(eoff + j)*64 + mg*4] = make_float4(acc[j][0], acc[j][1], acc[j][2], acc[j][3]);

    // stats partial reduce
    __syncthreads();
    if (xon) {
        redn[sx_t*64 + sx_e4+0] = s0; redn[sx_t*64 + sx_e4+1] = s1;
        redn[sx_t*64 + sx_e4+2] = s2; redn[sx_t*64 + sx_e4+3] = s3;
        reds[sx_t*64 + sx_e4+0] = q0; reds[sx_t*64 + sx_e4+1] = q1;
        reds[sx_t*64 + sx_e4+2] = q2; reds[sx_t*64 + sx_e4+3] = q3;
    }
    __syncthreads();
    if (tid < 64) {
        float s = 0.f, q = 0.f;
        #pragma unroll
        for (int rr = 0; rr < 12; rr++) { s += redn[rr*64 + tid]; q += reds[rr*64 + tid]; }
        const size_t o = (size_t)((tsp*16 + b)*6 + et)*64 + tid;
        gbuf[GB_PS_SUM + o] = s;
        gbuf[GB_PS_SS  + o] = q;
    }
}

// ---------------- k2b: reduce slabs+stats -> C (scaled), mean/stdev ----------------
// 96 blocks (b, et64), 256 thr.
__global__ __launch_bounds__(256) void k2b(const float* __restrict__ aw,
        const float* __restrict__ ab, const float* __restrict__ gbuf,
        float* __restrict__ ws)
{
    __shared__ float ssc[64], ssh[64], sksum[64];
    __shared__ float kred[4][64];
    const int tid = threadIdx.x;
    const int b = blockIdx.x / 6, et = blockIdx.x % 6;
    const int e0 = et*64;

    if (tid < 64) {
        float s = 0.f, q = 0.f;
        #pragma unroll
        for (int tsp = 0; tsp < 4; tsp++) {
            const size_t o = (size_t)((tsp*16 + b)*6 + et)*64 + tid;
            s += gbuf[GB_PS_SUM + o];
            q += gbuf[GB_PS_SS  + o];
        }
        float mean = s * (1.0f/SEQ);
        float var  = q * (1.0f/SEQ) - mean*mean;
        float sd   = sqrtf(var + 1e-5f);
        int e = e0 + tid;
        float a  = (e < ENC) ? aw[e] : 0.f;
        float av = (e < ENC) ? ab[e] : 0.f;
        float sc = a / sd;
        ssc[tid] = sc; ssh[tid] = av - mean*sc;
        if (e < ENC) {
            ws[WS_MEAN  + b*ENC + e] = mean;
            ws[WS_STDEV + b*ENC + e] = sd;
        }
    }
    // Ksum[m] = sum_t Kt[t][m]
    {
        const int m = tid & 63, g = tid >> 6;
        const float* Kt = ws + WS_KT;
        float s = 0.f;
        for (int r = g*180; r < (g+1)*180; r++) s += Kt[(size_t)r*64 + m];
        kred[g][m] = s;
    }
    __syncthreads();
    if (tid < 64) sksum[tid] = kred[0][tid] + kred[1][tid] + kred[2][tid] + kred[3][tid];
    __syncthreads();

    const float* g0 = gbuf + GB_G + (size_t)(b*6 + et)*4096;
    float* C = ws + WS_C;
    #pragma unroll
    for (int k = 0; k < 16; k++) {
        int idx = k*256 + tid;
        int el = idx >> 6, m = idx & 63;
        float gs = g0[idx] + g0[(size_t)96*4096 + idx]
                 + g0[(size_t)192*4096 + idx] + g0[(size_t)288*4096 + idx];
        int e = e0 + el;
        if (e < ENC)
            C[(size_t)(b*ENC + e)*64 + m] = ssc[el]*gs + ssh[el]*sksum[m];
    }
}

// ---------------- k3: out = C @ EW^T + evb, denorm — tp<PRED guards RESTORED ----------------
// grid 16b x 12 t'-tiles(64) x 6 e-tiles(64); 256 thr; last t'-tile covers tp 704..767,
// rows >= 720 MUST be masked (R5 bug: unguarded writes corrupted batch b+1 rows 0..47).
__global__ __launch_bounds__(256) void k3(const float* __restrict__ aw,
        const float* __restrict__ ab, const float* __restrict__ ws,
        float* __restrict__ out)
{
    __shared__ float EWt[64*68];   // [m][t'] transposed
    __shared__ float Ct[64*65];    // [el][m]
    const int tid = threadIdx.x;
    const int bid = blockIdx.x;
    const int b   = bid / 72;
    const int r   = bid % 72;
    const int tt0 = (r / 6) * 64;
    const int e0  = (r % 6) * 64;
    const int lane = tid & 63;
    const int tq   = tid >> 6;
    {
        const float* EW = ws + WS_EW;
        #pragma unroll
        for (int i = 0; i < 16; i++) {
            int tl = tq*16 + i;
            int tp = tt0 + tl;
            float v = (tp < PRED) ? EW[(size_t)tp*64 + lane] : 0.f;
            EWt[lane*68 + tl] = v;
        }
        const float* C = ws + WS_C + (size_t)(b*ENC + e0)*64;
        #pragma unroll
        for (int k = 0; k < 16; k++) {
            int idx = k*256 + tid;
            int el = idx >> 6, mm = idx & 63;
            float v = (e0 + el < ENC) ? C[idx] : 0.f;
            Ct[el*65 + mm] = v;
        }
    }
    __syncthreads();
    const int e = e0 + lane;
    const bool valid = e < ENC;
    const int p = b*ENC + e;

    float acc[16];
    #pragma unroll
    for (int i = 0; i < 16; i++) acc[i] = 0.f;
    #pragma unroll 4
    for (int m = 0; m < 64; m++) {
        float cv = Ct[lane*65 + m];
        const float* wr = &EWt[m*68 + tq*16];
        float4 w0 = *(const float4*)&wr[0];
        float4 w1 = *(const float4*)&wr[4];
        float4 w2 = *(const float4*)&wr[8];
        float4 w3 = *(const float4*)&wr[12];
        acc[0]+=w0.x*cv; acc[1]+=w0.y*cv; acc[2]+=w0.z*cv; acc[3]+=w0.w*cv;
        acc[4]+=w1.x*cv; acc[5]+=w1.y*cv; acc[6]+=w1.z*cv; acc[7]+=w1.w*cv;
        acc[8]+=w2.x*cv; acc[9]+=w2.y*cv; acc[10]+=w2.z*cv; acc[11]+=w2.w*cv;
        acc[12]+=w3.x*cv; acc[13]+=w3.y*cv; acc[14]+=w3.z*cv; acc[15]+=w3.w*cv;
    }
    float mean=0.f, sd=0.f, iaw=0.f, abe=0.f;
    if (valid) {
        mean = ws[WS_MEAN + p];
        sd   = ws[WS_STDEV + p];
        iaw  = 1.0f/(aw[e] + 1e-10f);
        abe  = ab[e];
    }
    const float* evb = ws + WS_EVB;
    #pragma unroll
    for (int i = 0; i < 16; i++) {
        int tp = tt0 + tq*16 + i;
        if (valid && tp < PRED) {
            float v = (acc[i] + evb[tp] - abe) * iaw * sd + mean;
            out[((size_t)b*PRED + tp)*ENC + e] = v;
        }
    }
}

extern "C" void kernel_launch(void* const* d_in, const int* in_sizes, int n_in,
                              void* d_out, int out_size, void* d_ws, size_t ws_size,
                              hipStream_t stream)
{
    const float* x     = (const float*)d_in[0];
    const float* A     = (const float*)d_in[1];
    const float* Bv    = (const float*)d_in[2];
    const float* evalm = (const float*)d_in[3];
    const float* W     = (const float*)d_in[4];
    const float* bm    = (const float*)d_in[5];
    const float* aw    = (const float*)d_in[6];
    const float* ab    = (const float*)d_in[7];
    float* ws  = (float*)d_ws;
    float* out = (float*)d_out;

    k1b<<<12, 1024, 0, stream>>>(evalm, W, bm, ws);
    p1 <<<1, 1024, 0, stream>>>(A, Bv, ws);
    p2 <<<8, 128, 0, stream>>>(ws);
    k2 <<<BATCH*6*4, 256, 0, stream>>>(x, out, ws);   // G + stats partials into d_out scratch
    k2b<<<BATCH*6, 256, 0, stream>>>(aw, ab, out, ws);
    k3 <<<1152, 256, 0, stream>>>(aw, ab, ws, out);
}

// Round 7
// 159.455 us; speedup vs baseline: 6.7204x; 1.1338x over previous
//
#include <hip/hip_runtime.h>
#include <math.h>

#define BATCH 16
#define SEQ   720
#define ENC   321
#define ENCP  324            // C row pad (16B-aligned rows)
#define NORD  64
#define PRED  720
#define NPAIR (BATCH*ENC)    // 5136

// ---- workspace layout (float offsets), ~1.76 MB ----
#define WS_MEAN   0
#define WS_STDEV  (WS_MEAN + NPAIR)          // 5136
#define WS_KT     (WS_STDEV + NPAIR)         // 10272  Kt[t][m] = (A^(719-t) B)[m]
#define WS_EWT    (WS_KT + PRED*NORD)        // 56352  EW^T [m][t'] (64 x 720)
#define WS_EVB    (WS_EWT + NORD*PRED)       // 102432 (720)
#define WS_C      (WS_EVB + PRED)            // 103152 C m-major [b][m][ENCP]
#define WS_A64    (WS_C + BATCH*NORD*ENCP)   // 434928 (64x64 = A^64)

// ---- d_out as scratch before k3 overwrites it ----
#define GB_G      0                          // 4 slabs x 96 tiles x 4096
#define GB_PS_SUM 1572864
#define GB_PS_SS  (GB_PS_SUM + 24576)

// ---------------- prep: [bid<12] EW^T = (eval@W)^T + evb | [bid==12] Krylov to A^64 ----------------
__global__ __launch_bounds__(1024) void prep(const float* __restrict__ evalm,
        const float* __restrict__ W, const float* __restrict__ bm,
        const float* __restrict__ A, const float* __restrict__ Bv,
        float* __restrict__ ws)
{
    extern __shared__ float dsm[];           // 12800 floats
    const int tid  = threadIdx.x;
    const int lane = tid & 63;
    const int wv   = tid >> 6;
    if (blockIdx.x < 12) {
        float* smW = dsm;                    // [n][m] pad 65 (4160)
        float* Et  = dsm + 64*65;            // [m][row] pad 61 (3904)
        const int r = blockIdx.x;
        for (int idx = tid; idx < 64*64; idx += 1024)
            smW[(idx>>6)*65 + (idx&63)] = W[idx];
        __syncthreads();
        float bv = bm[lane];
        #pragma unroll
        for (int k = 0; k < 4; k++) {
            int row = wv + k*16;
            if (row < 60) {
                int tp = r*60 + row;
                const float* ev = evalm + (size_t)tp*64;
                float acc = 0.f;
                #pragma unroll
                for (int kk = 0; kk < 16; kk++) {
                    float4 e4 = *(const float4*)&ev[4*kk];
                    acc += e4.x*smW[(4*kk+0)*65+lane] + e4.y*smW[(4*kk+1)*65+lane]
                         + e4.z*smW[(4*kk+2)*65+lane] + e4.w*smW[(4*kk+3)*65+lane];
                }
                Et[lane*61 + row] = acc;
                float pv = ev[lane] * bv;
                #pragma unroll
                for (int o = 32; o > 0; o >>= 1) pv += __shfl_down(pv, o);
                if (lane == 0) ws[WS_EVB + tp] = pv;
            }
        }
        __syncthreads();
        #pragma unroll
        for (int k = 0; k < 4; k++) {
            int idx = k*1024 + tid;          // 4096 slots, rows padded to 64
            int m = idx >> 6, row = idx & 63;
            if (row < 60)
                ws[WS_EWT + (size_t)m*720 + r*60 + row] = Et[m*61 + row];
        }
    } else {
        float* Kl  = dsm;                    // [64][64] rows j=0..63 (4096)
        float* Ap  = dsm + 4096;             // [64][68] A^m (4352)
        float* ApT = Ap + 64*68;             // [64][68] transposed
        float* Kt  = ws + WS_KT;
        for (int idx = tid; idx < 4096; idx += 1024) {
            int n = idx >> 6, m = idx & 63;
            float v = A[idx];
            Ap[n*68+m] = v; ApT[m*68+n] = v;
        }
        if (tid < 64) {
            float bv = Bv[tid];
            Kl[tid] = bv;
            Kt[(size_t)719*64 + tid] = bv;
        }
        __syncthreads();
        float ar[64];                        // row `lane` of A^m
        #pragma unroll
        for (int k = 0; k < 16; k++) {
            float4 v = *(const float4*)&Ap[lane*68 + 4*k];
            ar[4*k]=v.x; ar[4*k+1]=v.y; ar[4*k+2]=v.z; ar[4*k+3]=v.w;
        }
        for (int mm = 1; mm <= 32; mm <<= 1) {
            // expand rows mm..2mm-1:  K[j2] = A^mm @ K[j2-mm]
            for (int j2 = mm + wv; j2 < 2*mm; j2 += 16) {
                const float* src = &Kl[(j2 - mm)*64];
                float acc = 0.f;
                #pragma unroll
                for (int k = 0; k < 16; k++) {
                    float4 s = *(const float4*)&src[4*k];   // wave-uniform broadcast
                    acc += ar[4*k]*s.x + ar[4*k+1]*s.y + ar[4*k+2]*s.z + ar[4*k+3]*s.w;
                }
                Kl[j2*64 + lane] = acc;
                Kt[(size_t)(719 - j2)*64 + lane] = acc;
            }
            // square: A^(2mm) = A^mm @ A^mm
            float nacc[4];
            #pragma unroll
            for (int q = 0; q < 4; q++) {
                int c = wv*4 + q;
                const float* src = &ApT[c*68];
                float acc = 0.f;
                #pragma unroll
                for (int k = 0; k < 16; k++) {
                    float4 s = *(const float4*)&src[4*k];
                    acc += ar[4*k]*s.x + ar[4*k+1]*s.y + ar[4*k+2]*s.z + ar[4*k+3]*s.w;
                }
                nacc[q] = acc;
            }
            __syncthreads();
            #pragma unroll
            for (int q = 0; q < 4; q++) {
                int c = wv*4 + q;
                Ap[lane*68 + c]  = nacc[q];
                ApT[c*68 + lane] = nacc[q];
            }
            __syncthreads();
            #pragma unroll
            for (int k = 0; k < 16; k++) {
                float4 v = *(const float4*)&Ap[lane*68 + 4*k];
                ar[4*k]=v.x; ar[4*k+1]=v.y; ar[4*k+2]=v.z; ar[4*k+3]=v.w;
            }
        }
        // Ap holds A^64
        for (int idx = tid; idx < 4096; idx += 1024)
            ws[WS_A64 + idx] = Ap[(idx>>6)*68 + (idx&63)];
    }
}

// ---------------- p2: 64 parallel chains K[r+64q] = A^64 K[r+64(q-1)] ----------------
// 16 blocks x 256 thr (4 waves = 4 chains/block); <=11 serial steps per chain.
__global__ __launch_bounds__(256) void p2(float* __restrict__ ws)
{
    __shared__ float sv[4][64];
    const int lane = threadIdx.x & 63;
    const int wv   = threadIdx.x >> 6;
    const int r    = blockIdx.x*4 + wv;          // chain 0..63
    const float* A64 = ws + WS_A64;
    float* Kt = ws + WS_KT;
    float ar64[64];
    #pragma unroll
    for (int k = 0; k < 16; k++) {
        float4 v = *(const float4*)&A64[lane*64 + 4*k];
        ar64[4*k]=v.x; ar64[4*k+1]=v.y; ar64[4*k+2]=v.z; ar64[4*k+3]=v.w;
    }
    sv[wv][lane] = Kt[(size_t)(719 - r)*64 + lane];
    for (int j = r + 64; j <= 719; j += 64) {
        float acc = 0.f;
        #pragma unroll
        for (int k = 0; k < 16; k++) {
            float4 v = *(const float4*)&sv[wv][4*k];
            acc += ar64[4*k]*v.x + ar64[4*k+1]*v.y + ar64[4*k+2]*v.z + ar64[4*k+3]*v.w;
        }
        sv[wv][lane] = acc;                       // same-wave DS ordering
        Kt[(size_t)(719 - j)*64 + lane] = acc;
    }
}

// ---------------- k2: G[p][m] = sum_t x[p][t] K[t][m] + stats partials (unchanged) ----------------
__device__ inline float4 ldx(const float* __restrict__ x, int b, int t, int e4)
{
    float4 r = make_float4(0.f,0.f,0.f,0.f);
    const float* p = x + ((size_t)b*SEQ + t)*ENC;
    if (e4 + 3 < ENC) r = *(const float4*)&p[e4];
    else {
        if (e4   < ENC) r.x = p[e4];
        if (e4+1 < ENC) r.y = p[e4+1];
        if (e4+2 < ENC) r.z = p[e4+2];
    }
    return r;
}

__global__ __launch_bounds__(256) void k2(const float* __restrict__ x,
        float* __restrict__ gbuf, const float* __restrict__ ws)
{
    __shared__ float xt[2][12*64];
    __shared__ float ks[2][12*64];
    __shared__ float redn[12*64];
    __shared__ float reds[12*64];
    const int tid = threadIdx.x;
    const int bid = blockIdx.x;
    const int b = bid / 24, rem = bid % 24;
    const int et = rem / 4, tsp = rem % 4;
    const int e0 = et*64, t0 = tsp*180;

    const bool xon = tid < 192;
    const bool kon = tid >= 64;
    const int sx_t  = tid >> 4;
    const int sx_e4 = (tid & 15) * 4;
    const int sk    = tid - 64;
    const int sk_t  = sk >> 4;
    const int sk_m4 = (sk & 15) * 4;

    const float* Kt = ws + WS_KT;
    float s0=0,s1=0,s2=0,s3=0, q0=0,q1=0,q2=0,q3=0;
    float4 rx = make_float4(0,0,0,0), rk = make_float4(0,0,0,0);

    if (xon) rx = ldx(x, b, t0 + sx_t, e0 + sx_e4);
    if (kon) rk = *(const float4*)&Kt[(size_t)(t0 + sk_t)*64 + sk_m4];
    if (xon) {
        *(float4*)&xt[0][sx_t*64 + sx_e4] = rx;
        s0+=rx.x; s1+=rx.y; s2+=rx.z; s3+=rx.w;
        q0+=rx.x*rx.x; q1+=rx.y*rx.y; q2+=rx.z*rx.z; q3+=rx.w*rx.w;
    }
    if (kon) *(float4*)&ks[0][sk_t*64 + sk_m4] = rk;

    const int lane = tid & 63, wv = tid >> 6;
    const int mg = lane & 15, eg = lane >> 4;
    const int eoff = wv*16 + eg*4;
    float acc[4][4];
    #pragma unroll
    for (int j = 0; j < 4; j++)
        #pragma unroll
        for (int i = 0; i < 4; i++) acc[j][i] = 0.f;

    for (int ch = 0; ch < 15; ch++) {
        if (ch + 1 < 15) {
            if (xon) rx = ldx(x, b, t0 + (ch+1)*12 + sx_t, e0 + sx_e4);
            if (kon) rk = *(const float4*)&Kt[(size_t)(t0 + (ch+1)*12 + sk_t)*64 + sk_m4];
        }
        __syncthreads();
        const float* xb = xt[ch & 1];
        const float* kb = ks[ch & 1];
        #pragma unroll
        for (int tt = 0; tt < 12; tt++) {
            float4 f  = *(const float4*)&xb[tt*64 + eoff];
            float4 kv = *(const float4*)&kb[tt*64 + mg*4];
            acc[0][0]+=f.x*kv.x; acc[0][1]+=f.x*kv.y; acc[0][2]+=f.x*kv.z; acc[0][3]+=f.x*kv.w;
            acc[1][0]+=f.y*kv.x; acc[1][1]+=f.y*kv.y; acc[1][2]+=f.y*kv.z; acc[1][3]+=f.y*kv.w;
            acc[2][0]+=f.z*kv.x; acc[2][1]+=f.z*kv.y; acc[2][2]+=f.z*kv.z; acc[2][3]+=f.z*kv.w;
            acc[3][0]+=f.w*kv.x; acc[3][1]+=f.w*kv.y; acc[3][2]+=f.w*kv.z; acc[3][3]+=f.w*kv.w;
        }
        if (ch + 1 < 15) {
            if (xon) {
                *(float4*)&xt[(ch+1)&1][sx_t*64 + sx_e4] = rx;
                s0+=rx.x; s1+=rx.y; s2+=rx.z; s3+=rx.w;
                q0+=rx.x*rx.x; q1+=rx.y*rx.y; q2+=rx.z*rx.z; q3+=rx.w*rx.w;
            }
            if (kon) *(float4*)&ks[(ch+1)&1][sk_t*64 + sk_m4] = rk;
        }
    }

    float* g = gbuf + GB_G + (size_t)(tsp*96 + b*6 + et)*4096;
    #pragma unroll
    for (int j = 0; j < 4; j++)
        *(float4*)&g[(eoff + j)*64 + mg*4] = make_float4(acc[j][0], acc[j][1], acc[j][2], acc[j][3]);

    __syncthreads();
    if (xon) {
        redn[sx_t*64 + sx_e4+0] = s0; redn[sx_t*64 + sx_e4+1] = s1;
        redn[sx_t*64 + sx_e4+2] = s2; redn[sx_t*64 + sx_e4+3] = s3;
        reds[sx_t*64 + sx_e4+0] = q0; reds[sx_t*64 + sx_e4+1] = q1;
        reds[sx_t*64 + sx_e4+2] = q2; reds[sx_t*64 + sx_e4+3] = q3;
    }
    __syncthreads();
    if (tid < 64) {
        float s = 0.f, q = 0.f;
        #pragma unroll
        for (int rr = 0; rr < 12; rr++) { s += redn[rr*64 + tid]; q += reds[rr*64 + tid]; }
        const size_t o = (size_t)((tsp*16 + b)*6 + et)*64 + tid;
        gbuf[GB_PS_SUM + o] = s;
        gbuf[GB_PS_SS  + o] = q;
    }
}

// ---------------- k2b: slabs+stats -> C m-major [b][m][ENCP] (LDS transpose) ----------------
__global__ __launch_bounds__(256) void k2b(const float* __restrict__ aw,
        const float* __restrict__ ab, const float* __restrict__ gbuf,
        float* __restrict__ ws)
{
    __shared__ float ssc[64], ssh[64], sksum[64];
    __shared__ float kred[4][64];
    __shared__ float T[64*65];          // [m][el]
    const int tid = threadIdx.x;
    const int b = blockIdx.x / 6, et = blockIdx.x % 6;
    const int e0 = et*64;

    if (tid < 64) {
        float s = 0.f, q = 0.f;
        #pragma unroll
        for (int tsp = 0; tsp < 4; tsp++) {
            const size_t o = (size_t)((tsp*16 + b)*6 + et)*64 + tid;
            s += gbuf[GB_PS_SUM + o];
            q += gbuf[GB_PS_SS  + o];
        }
        float mean = s * (1.0f/SEQ);
        float var  = q * (1.0f/SEQ) - mean*mean;
        float sd   = sqrtf(var + 1e-5f);
        int e = e0 + tid;
        float a  = (e < ENC) ? aw[e] : 0.f;
        float av = (e < ENC) ? ab[e] : 0.f;
        float sc = a / sd;
        ssc[tid] = sc; ssh[tid] = av - mean*sc;
        if (e < ENC) {
            ws[WS_MEAN  + b*ENC + e] = mean;
            ws[WS_STDEV + b*ENC + e] = sd;
        }
    }
    {
        const int m = tid & 63, g = tid >> 6;
        const float* Kt = ws + WS_KT;
        float s = 0.f;
        for (int r = g*180; r < (g+1)*180; r++) s += Kt[(size_t)r*64 + m];
        kred[g][m] = s;
    }
    __syncthreads();
    if (tid < 64) sksum[tid] = kred[0][tid] + kred[1][tid] + kred[2][tid] + kred[3][tid];
    __syncthreads();

    const float* g0 = gbuf + GB_G + (size_t)(b*6 + et)*4096;
    #pragma unroll
    for (int k = 0; k < 16; k++) {
        int idx = k*256 + tid;
        int el = idx >> 6, m = idx & 63;
        float gs = g0[idx] + g0[(size_t)96*4096 + idx]
                 + g0[(size_t)192*4096 + idx] + g0[(size_t)288*4096 + idx];
        T[m*65 + el] = ssc[el]*gs + ssh[el]*sksum[m];
    }
    __syncthreads();
    float* C = ws + WS_C + (size_t)b*64*ENCP;
    #pragma unroll
    for (int k = 0; k < 16; k++) {
        int idx = k*256 + tid;
        int m = idx >> 6, el = idx & 63;
        int e = e0 + el;
        if (e < ENCP) C[(size_t)m*ENCP + e] = (e < ENC) ? T[m*65 + el] : 0.f;
    }
}

// ---------------- k3: out = C @ EW^T + evb, denorm — 8x4 register tile ----------------
// grid 16b x 12 t'-tiles(64) x 3 e-tiles(128) = 576; 256 thr; thread = 8 t' x 4 e.
__global__ __launch_bounds__(256) void k3(const float* __restrict__ aw,
        const float* __restrict__ ab, const float* __restrict__ ws,
        float* __restrict__ out)
{
    __shared__ float EWm[64*68];   // [m][t' 64]
    __shared__ float Cm[64*132];   // [m][e 128]
    const int tid = threadIdx.x;
    const int b   = blockIdx.x / 36;
    const int r   = blockIdx.x % 36;
    const int tt0 = (r / 3) * 64;
    const int e0  = (r % 3) * 128;

    const float* EWT = ws + WS_EWT;
    #pragma unroll
    for (int k = 0; k < 4; k++) {           // 1024 b128 slots
        int slot = k*256 + tid;
        int m = slot >> 4, t4 = (slot & 15)*4;
        int tp = tt0 + t4;
        float4 v;
        if (tp + 3 < PRED) v = *(const float4*)&EWT[(size_t)m*720 + tp];
        else {
            v = make_float4(0.f,0.f,0.f,0.f);
            if (tp   < PRED) v.x = EWT[(size_t)m*720 + tp];
            if (tp+1 < PRED) v.y = EWT[(size_t)m*720 + tp+1];
            if (tp+2 < PRED) v.z = EWT[(size_t)m*720 + tp+2];
        }
        *(float4*)&EWm[m*68 + t4] = v;
    }
    const float* C = ws + WS_C + (size_t)b*64*ENCP;
    #pragma unroll
    for (int k = 0; k < 8; k++) {           // 2048 b128 slots
        int slot = k*256 + tid;
        int m = slot >> 5, e4 = (slot & 31)*4;
        float4 v = make_float4(0.f,0.f,0.f,0.f);
        if (e0 + e4 + 3 < ENCP) v = *(const float4*)&C[(size_t)m*ENCP + e0 + e4];
        *(float4*)&Cm[m*132 + e4] = v;
    }
    __syncthreads();

    const int tx = tid & 31;                // e-group (4 e)
    const int ty = tid >> 5;                // t'-group (8 t')
    float acc[8][4];
    #pragma unroll
    for (int i = 0; i < 8; i++)
        #pragma unroll
        for (int j = 0; j < 4; j++) acc[i][j] = 0.f;

    #pragma unroll 4
    for (int m = 0; m < 64; m++) {
        float4 c4 = *(const float4*)&Cm[m*132 + tx*4];
        float4 w0 = *(const float4*)&EWm[m*68 + ty*8];
        float4 w1 = *(const float4*)&EWm[m*68 + ty*8 + 4];
        acc[0][0]+=w0.x*c4.x; acc[0][1]+=w0.x*c4.y; acc[0][2]+=w0.x*c4.z; acc[0][3]+=w0.x*c4.w;
        acc[1][0]+=w0.y*c4.x; acc[1][1]+=w0.y*c4.y; acc[1][2]+=w0.y*c4.z; acc[1][3]+=w0.y*c4.w;
        acc[2][0]+=w0.z*c4.x; acc[2][1]+=w0.z*c4.y; acc[2][2]+=w0.z*c4.z; acc[2][3]+=w0.z*c4.w;
        acc[3][0]+=w0.w*c4.x; acc[3][1]+=w0.w*c4.y; acc[3][2]+=w0.w*c4.z; acc[3][3]+=w0.w*c4.w;
        acc[4][0]+=w1.x*c4.x; acc[4][1]+=w1.x*c4.y; acc[4][2]+=w1.x*c4.z; acc[4][3]+=w1.x*c4.w;
        acc[5][0]+=w1.y*c4.x; acc[5][1]+=w1.y*c4.y; acc[5][2]+=w1.y*c4.z; acc[5][3]+=w1.y*c4.w;
        acc[6][0]+=w1.z*c4.x; acc[6][1]+=w1.z*c4.y; acc[6][2]+=w1.z*c4.z; acc[6][3]+=w1.z*c4.w;
        acc[7][0]+=w1.w*c4.x; acc[7][1]+=w1.w*c4.y; acc[7][2]+=w1.w*c4.z; acc[7][3]+=w1.w*c4.w;
    }

    const int ebase = e0 + tx*4;
    float mean[4], sd[4], iaw[4], abe[4];
    #pragma unroll
    for (int j = 0; j < 4; j++) {
        int e = ebase + j;
        if (e < ENC) {
            int p = b*ENC + e;
            mean[j] = ws[WS_MEAN + p];
            sd[j]   = ws[WS_STDEV + p];
            iaw[j]  = 1.0f/(aw[e] + 1e-10f);
            abe[j]  = ab[e];
        } else { mean[j]=0.f; sd[j]=0.f; iaw[j]=0.f; abe[j]=0.f; }
    }
    const float* evb = ws + WS_EVB;
    #pragma unroll
    for (int i = 0; i < 8; i++) {
        int tp = tt0 + ty*8 + i;
        if (tp < PRED) {
            float ev = evb[tp];
            float* op = out + ((size_t)b*PRED + tp)*ENC;
            #pragma unroll
            for (int j = 0; j < 4; j++) {
                int e = ebase + j;
                if (e < ENC)
                    op[e] = (acc[i][j] + ev - abe[j]) * iaw[j] * sd[j] + mean[j];
            }
        }
    }
}

extern "C" void kernel_launch(void* const* d_in, const int* in_sizes, int n_in,
                              void* d_out, int out_size, void* d_ws, size_t ws_size,
                              hipStream_t stream)
{
    const float* x     = (const float*)d_in[0];
    const float* A     = (const float*)d_in[1];
    const float* Bv    = (const float*)d_in[2];
    const float* evalm = (const float*)d_in[3];
    const float* W     = (const float*)d_in[4];
    const float* bm    = (const float*)d_in[5];
    const float* aw    = (const float*)d_in[6];
    const float* ab    = (const float*)d_in[7];
    float* ws  = (float*)d_ws;
    float* out = (float*)d_out;

    const size_t smbytes = 12800 * sizeof(float);   // 51.2 KB
    hipFuncSetAttribute((const void*)prep, hipFuncAttributeMaxDynamicSharedMemorySize, (int)smbytes);

    prep<<<13, 1024, smbytes, stream>>>(evalm, W, bm, A, Bv, ws);
    p2  <<<16, 256, 0, stream>>>(ws);
    k2  <<<BATCH*6*4, 256, 0, stream>>>(x, out, ws);
    k2b <<<BATCH*6, 256, 0, stream>>>(aw, ab, out, ws);
    k3  <<<576, 256, 0, stream>>>(aw, ab, ws, out);
}